// Round 4
// baseline (715.106 us; speedup 1.0000x reference)
//
#include <hip/hip_runtime.h>
#include <hip/hip_bf16.h>
#include <hip/hip_fp16.h>

typedef _Float16 f16;
typedef _Float16 f16x4 __attribute__((ext_vector_type(4)));
typedef _Float16 f16x8 __attribute__((ext_vector_type(8)));
typedef float f32x4 __attribute__((ext_vector_type(4)));

#define NB 8192
#define ND 1024
#define NU 1024
#define NE 16
#define BM 64      // rows per block
#define BUH 512    // cols per block (U half)
#define NRT 128    // row tiles
#define WT_BYTES ((size_t)NE * NU * ND * 2)            // 33,554,432
#define SUMS_FLOATS ((size_t)NE * NRT * 2 * 64)        // 1 MB
#define FLG_INTS ((size_t)NE * NRT * 2)                // 4096 ints
#define SYNC_INTS ((size_t)NE * 8)

// ---------------- prep: transpose-cast W [E][D][U] f32 -> WT [E][U][D] f16 ----------------
__global__ __launch_bounds__(256) void k_transpose_cast(const float* __restrict__ W,
                                                        f16* __restrict__ WT) {
  __shared__ f16 tile[64][68];
  const int e = blockIdx.z;
  const int u0 = blockIdx.x * 64;
  const int d0 = blockIdx.y * 64;
  const int t = threadIdx.x;
  const int r = t >> 4;
  const int c = (t & 15) << 2;
  const float* src = W + (size_t)e * ND * NU;
  f16* dst = WT + (size_t)e * NU * ND;
#pragma unroll
  for (int i = 0; i < 4; ++i) {
    const int rr = r + i * 16;
    const float4 v = *(const float4*)(src + (size_t)(d0 + rr) * NU + (u0 + c));
    tile[rr][c + 0] = (f16)v.x;
    tile[rr][c + 1] = (f16)v.y;
    tile[rr][c + 2] = (f16)v.z;
    tile[rr][c + 3] = (f16)v.w;
  }
  __syncthreads();
#pragma unroll
  for (int i = 0; i < 4; ++i) {
    const int rr = r + i * 16;
    f16x4 h;
    h[0] = tile[c + 0][rr];
    h[1] = tile[c + 1][rr];
    h[2] = tile[c + 2][rr];
    h[3] = tile[c + 3][rr];
    *(f16x4*)(dst + (size_t)(u0 + rr) * ND + (d0 + c)) = h;
  }
}

// ---------------- main ----------------
// 256 blocks x 512 threads, 1/CU. XCD-aligned: xcd=bid&7 fixes the column half so all
// 32 blocks of an XCD read the SAME W stream; per-(e,xcd) pacing barrier keeps them in
// the same L2-resident 1MB panel; per-block k-rotation de-correlates same-line access.

#define LOADB(F, soff)                                   \
  {                                                      \
    const char* p_ = wtc + (soff) + vbase;               \
    F[0] = *(const f16x8*)(p_);                          \
    F[1] = *(const f16x8*)(p_ + 1 * 16 * ND * 2);        \
    F[2] = *(const f16x8*)(p_ + 2 * 16 * ND * 2);        \
    F[3] = *(const f16x8*)(p_ + 3 * 16 * ND * 2);        \
  }

#define MFMA_HALF(F, kbyte)                                                         \
  {                                                                                 \
    const f16x8 a0 = *(const f16x8*)(A_s + (ln + 0) * 2064 + g * 16 + (kbyte));     \
    const f16x8 a1 = *(const f16x8*)(A_s + (ln + 16) * 2064 + g * 16 + (kbyte));    \
    const f16x8 a2 = *(const f16x8*)(A_s + (ln + 32) * 2064 + g * 16 + (kbyte));    \
    const f16x8 a3 = *(const f16x8*)(A_s + (ln + 48) * 2064 + g * 16 + (kbyte));    \
    _Pragma("unroll") for (int n_ = 0; n_ < 4; ++n_) {                              \
      acc[0][n_] = __builtin_amdgcn_mfma_f32_16x16x32_f16(a0, F[n_], acc[0][n_], 0, 0, 0); \
      acc[1][n_] = __builtin_amdgcn_mfma_f32_16x16x32_f16(a1, F[n_], acc[1][n_], 0, 0, 0); \
      acc[2][n_] = __builtin_amdgcn_mfma_f32_16x16x32_f16(a2, F[n_], acc[2][n_], 0, 0, 0); \
      acc[3][n_] = __builtin_amdgcn_mfma_f32_16x16x32_f16(a3, F[n_], acc[3][n_], 0, 0, 0); \
    }                                                                               \
  }

__global__ __launch_bounds__(512, 2) void k_proj(const float* __restrict__ X,
                                                 const float* __restrict__ TP,
                                                 const f16* __restrict__ WT,
                                                 const float* __restrict__ BIAS,
                                                 float* __restrict__ OUT,
                                                 float* __restrict__ SUMS,
                                                 int* __restrict__ FLG,
                                                 int* __restrict__ SYNC) {
  __shared__ alignas(16) unsigned char lds[132096 + 4096 + 2048 + 256];
  unsigned char* A_s = lds;
  float* tp_s = (float*)(lds + 132096);
  float* reds = (float*)(lds + 132096 + 4096);
  float* sums_s = (float*)(lds + 132096 + 4096 + 2048);

  const int t = threadIdx.x;
  const int w = t >> 6;
  const int l = t & 63;
  const int g = l >> 4;
  const int ln = l & 15;
  const int bid = blockIdx.x;
  const int xcd = bid & 7;          // presumed XCD (round-robin dispatch)
  const int j = bid >> 3;           // index within XCD, 0..31
  const int uh = xcd & 1;           // column half, constant per XCD
  const int rt = j + (xcd >> 1) * 32;
  const int b0 = rt * BM;
  const int c0 = uh * BUH;
  const int rot = j & 31;           // per-block k-rotation

  // ---- stage A panel (64 x 1024) fp32 -> fp16 in LDS ----
#pragma unroll
  for (int i = 0; i < 32; ++i) {
    const int idx = (i * 512 + t) << 2;
    const int row = idx >> 10;
    const int col = idx & 1023;
    const float4 v = *(const float4*)(X + (size_t)(b0 + row) * ND + col);
    f16x4 h;
    h[0] = (f16)v.x; h[1] = (f16)v.y; h[2] = (f16)v.z; h[3] = (f16)v.w;
    *(f16x4*)(A_s + row * 2064 + (col << 1)) = h;
  }
  tp_s[t] = TP[(size_t)(b0 + (t >> 4)) * NE + (t & 15)];
  tp_s[512 + t] = TP[(size_t)(b0 + 32 + (t >> 4)) * NE + (t & 15)];
  __syncthreads();

  f32x4 out_acc[4][4];
#pragma unroll
  for (int m = 0; m < 4; ++m)
#pragma unroll
    for (int n = 0; n < 4; ++n) out_acc[m][n] = (f32x4){0.f, 0.f, 0.f, 0.f};

  const char* wtc = (const char*)WT;
  const unsigned vbase = ((unsigned)(c0 + w * 64 + ln) * ND + g * 8) * 2;

  f16x8 F0[4], F1[4], F2[4], F3[4];

  for (int e = 0; e < NE; ++e) {
    // ---- per-(e,XCD) pacing barrier: keep the 32 same-XCD blocks in the same
    // 1MB panel so it stays L2-resident. Bounded spin => deadlock-free.
    if (t == 0) {
      int* ctr = &SYNC[e * 8 + xcd];
      __hip_atomic_fetch_add(ctr, 1, __ATOMIC_RELAXED, __HIP_MEMORY_SCOPE_AGENT);
      int spin = 0;
      while (__hip_atomic_load(ctr, __ATOMIC_RELAXED, __HIP_MEMORY_SCOPE_AGENT) < 32 &&
             spin < 150000) {
        __builtin_amdgcn_s_sleep(4);
        ++spin;
      }
    }
    __syncthreads();

    f32x4 acc[4][4];
#pragma unroll
    for (int m = 0; m < 4; ++m)
#pragma unroll
      for (int n = 0; n < 4; ++n) acc[m][n] = (f32x4){0.f, 0.f, 0.f, 0.f};

    // rotated k-order: half-step h(i) = (i + rot) & 31; GEMM sum is commutative.
    const size_t ebase = (size_t)e * ((size_t)NU * ND * 2);
#define SOFF(i) (ebase + (size_t)(((i) + rot) & 31) * 64)
#define KB(i) ((((i) + rot) & 31) * 64)

    LOADB(F0, SOFF(0));
    LOADB(F1, SOFF(1));
    LOADB(F2, SOFF(2));
#pragma unroll 1
    for (int gi = 0; gi < 7; ++gi) {
      const int base = gi * 4;
      LOADB(F3, SOFF(base + 3));
      MFMA_HALF(F0, KB(base + 0));
      LOADB(F0, SOFF(base + 4));
      MFMA_HALF(F1, KB(base + 1));
      LOADB(F1, SOFF(base + 5));
      MFMA_HALF(F2, KB(base + 2));
      LOADB(F2, SOFF(base + 6));
      MFMA_HALF(F3, KB(base + 3));
    }
    LOADB(F3, SOFF(31));
    MFMA_HALF(F0, KB(28));
    MFMA_HALF(F1, KB(29));
    MFMA_HALF(F2, KB(30));
    MFMA_HALF(F3, KB(31));
#undef SOFF
#undef KB

    // ---- epilogue: bias + exp (no max-sub; fp32-safe here) + row-sum + pair exchange ----
    const float* bp = BIAS + (size_t)e * NU + c0 + w * 64 + ln;
    float bv[4];
#pragma unroll
    for (int n = 0; n < 4; ++n) bv[n] = bp[n * 16];

    float rs[4][4];
#pragma unroll
    for (int m = 0; m < 4; ++m)
#pragma unroll
      for (int r = 0; r < 4; ++r) rs[m][r] = 0.f;
#pragma unroll
    for (int m = 0; m < 4; ++m)
#pragma unroll
      for (int n = 0; n < 4; ++n)
#pragma unroll
        for (int r = 0; r < 4; ++r) {
          const float p = __expf(acc[m][n][r] + bv[n]);
          acc[m][n][r] = p;
          rs[m][r] += p;
        }
#pragma unroll
    for (int m = 0; m < 4; ++m)
#pragma unroll
      for (int r = 0; r < 4; ++r) {
        float v = rs[m][r];
        v += __shfl_xor(v, 1, 64);
        v += __shfl_xor(v, 2, 64);
        v += __shfl_xor(v, 4, 64);
        v += __shfl_xor(v, 8, 64);
        rs[m][r] = v;
      }
    if (ln == 0) {
#pragma unroll
      for (int m = 0; m < 4; ++m)
#pragma unroll
        for (int r = 0; r < 4; ++r) reds[(m * 16 + g * 4 + r) * 8 + w] = rs[m][r];
    }
    __syncthreads();

    const int pairbase = (e * NRT + rt) * 2;
    float myS = 0.f;
    if (t < 64) {
      const float* rp = reds + t * 8;
      myS = ((rp[0] + rp[1]) + (rp[2] + rp[3])) + ((rp[4] + rp[5]) + (rp[6] + rp[7]));
      __hip_atomic_store(&SUMS[(size_t)(pairbase + uh) * 64 + t], myS,
                         __ATOMIC_RELAXED, __HIP_MEMORY_SCOPE_AGENT);
    }
    __syncthreads();
    if (t == 0) {
      __threadfence();
      __hip_atomic_store(&FLG[pairbase + uh], 1, __ATOMIC_RELEASE, __HIP_MEMORY_SCOPE_AGENT);
      int spin = 0;
      while (__hip_atomic_load(&FLG[pairbase + (uh ^ 1)], __ATOMIC_ACQUIRE,
                               __HIP_MEMORY_SCOPE_AGENT) == 0 &&
             spin < 400000) {
        __builtin_amdgcn_s_sleep(2);
        ++spin;
      }
    }
    __syncthreads();
    if (t < 64) {
      const float ps = __hip_atomic_load(&SUMS[(size_t)(pairbase + (uh ^ 1)) * 64 + t],
                                         __ATOMIC_RELAXED, __HIP_MEMORY_SCOPE_AGENT);
      sums_s[t] = myS + ps;
    }
    __syncthreads();

#pragma unroll
    for (int m = 0; m < 4; ++m)
#pragma unroll
      for (int r = 0; r < 4; ++r) {
        const int row = m * 16 + g * 4 + r;
        const float scale = tp_s[row * 16 + e] * __builtin_amdgcn_rcpf(sums_s[row]);
#pragma unroll
        for (int n = 0; n < 4; ++n) out_acc[m][n][r] += scale * acc[m][n][r];
      }
  }

  // ---- write out [64][512] fp32 (disjoint per block) ----
#pragma unroll
  for (int m = 0; m < 4; ++m)
#pragma unroll
    for (int r = 0; r < 4; ++r) {
      float* op = OUT + (size_t)(b0 + m * 16 + g * 4 + r) * NU + c0 + w * 64 + ln;
#pragma unroll
      for (int n = 0; n < 4; ++n) op[n * 16] = out_acc[m][n][r];
    }
}

extern "C" void kernel_launch(void* const* d_in, const int* in_sizes, int n_in,
                              void* d_out, int out_size, void* d_ws, size_t ws_size,
                              hipStream_t stream) {
  const float* X = (const float*)d_in[0];     // [8192,1024] f32
  const float* TP = (const float*)d_in[1];    // [8192,16,1] f32
  const float* W = (const float*)d_in[2];     // [16,1024,1024] f32
  const float* BIAS = (const float*)d_in[3];  // [16,1024] f32
  float* OUT = (float*)d_out;                 // [8192,1024] f32

  f16* WT = (f16*)d_ws;                                          // 33.5 MB
  float* SUMS = (float*)((char*)d_ws + WT_BYTES);                // 1 MB
  int* FLG = (int*)((char*)d_ws + WT_BYTES + SUMS_FLOATS * 4);   // 16 KB
  int* SYNC = (int*)((char*)d_ws + WT_BYTES + SUMS_FLOATS * 4 + FLG_INTS * 4);

  hipMemsetAsync(FLG, 0, (FLG_INTS + SYNC_INTS) * sizeof(int), stream);
  k_transpose_cast<<<dim3(16, 16, 16), dim3(256), 0, stream>>>(W, WT);
  k_proj<<<dim3(256), dim3(512), 0, stream>>>(X, TP, WT, BIAS, OUT, SUMS, FLG, SYNC);
}